// Round 5
// baseline (3019.814 us; speedup 1.0000x reference)
//
#include <hip/hip_runtime.h>
#include <stdint.h>

#define TT 8192
#define HD 2048
#define FFN 5632
#define NE 8
#define BK 32

typedef float f32x4 __attribute__((ext_vector_type(4)));
typedef _Float16 f16x8 __attribute__((ext_vector_type(8)));
typedef unsigned int u32;

// workspace layout (bytes)
#define OFF_WR    0ul
#define OFF_CNT   65536ul
#define OFF_LISTS 66048ul
#define OFF_TOKW  328192ul
#define OFF_ACT   1048576ul                    // 16384*5632*2
#define OFF_XH    (OFF_ACT + 184549376ul)      // 8192*2048*2
#define OFF_W1H   (OFF_XH + 33554432ul)        // 8*5632*2048*2
#define OFF_W2H   (OFF_W1H + 184549376ul)
#define OFF_W3H   OFF_W1H                      // fc2h reuses W1H (stream-ordered)

__device__ __forceinline__ void gl_lds16(const void* g, void* s) {
  __builtin_amdgcn_global_load_lds((const __attribute__((address_space(1))) u32*)g,
                                   (__attribute__((address_space(3))) u32*)s, 16, 0, 0);
}

// XOR swizzle on byte offsets: selector bits 7-9, target bits 4-6 (involution).
__device__ __forceinline__ int swz(int b) { return b ^ (((b >> 7) & 7) << 4); }

#define WAIT_VM4() asm volatile("s_waitcnt vmcnt(4)" ::: "memory")
#define WAIT_VM0() asm volatile("s_waitcnt vmcnt(0)" ::: "memory")

__device__ __forceinline__ f16x8 cvt8(f32x4 a, f32x4 b) {
  f16x8 r;
  r[0] = (_Float16)a[0]; r[1] = (_Float16)a[1]; r[2] = (_Float16)a[2]; r[3] = (_Float16)a[3];
  r[4] = (_Float16)b[0]; r[5] = (_Float16)b[1]; r[6] = (_Float16)b[2]; r[7] = (_Float16)b[3];
  return r;
}

__global__ __launch_bounds__(256) void k_cvt(const float* __restrict__ in,
                                             _Float16* __restrict__ out, long n8) {
  long i = (long)blockIdx.x * 256 + threadIdx.x;
  const long stride = (long)gridDim.x * 256;
  for (; i < n8; i += stride) {
    f32x4 a = ((const f32x4*)in)[i * 2];
    f32x4 b = ((const f32x4*)in)[i * 2 + 1];
    ((f16x8*)out)[i] = cvt8(a, b);
  }
}

__global__ __launch_bounds__(256) void k_prep(const float* __restrict__ wg,
                                              const float* __restrict__ wge,
                                              float* __restrict__ wr) {
  int i = blockIdx.x * 256 + threadIdx.x;
  if (i < HD * NE) wr[i] = 0.5f * (wge[i] + wg[i]);
}

__global__ __launch_bounds__(256) void k_router(const float* __restrict__ x,
                                                const float* __restrict__ wr,
                                                float* __restrict__ logits,
                                                float* __restrict__ tokw,
                                                int* __restrict__ lists,
                                                int* __restrict__ cnt) {
  const int t = blockIdx.x, tid = threadIdx.x;
  const float* xr = x + (size_t)t * HD;
  float acc[NE];
#pragma unroll
  for (int e = 0; e < NE; ++e) acc[e] = 0.f;
  for (int h = tid; h < HD; h += 256) {
    float xv = xr[h];
    const float* w = wr + h * NE;
#pragma unroll
    for (int e = 0; e < NE; ++e) acc[e] = fmaf(xv, w[e], acc[e]);
  }
#pragma unroll
  for (int e = 0; e < NE; ++e)
#pragma unroll
    for (int off = 32; off; off >>= 1)
      acc[e] += __shfl_xor(acc[e], off, 64);
  __shared__ float red[4][NE];
  int wv = tid >> 6;
  if ((tid & 63) == 0)
    for (int e = 0; e < NE; ++e) red[wv][e] = acc[e];
  __syncthreads();
  if (tid == 0) {
    float l[NE];
#pragma unroll
    for (int e = 0; e < NE; ++e) l[e] = red[0][e] + red[1][e] + red[2][e] + red[3][e];
#pragma unroll
    for (int e = 0; e < NE; ++e) logits[(size_t)t * NE + e] = l[e];
    int i0 = 0;
    for (int e = 1; e < NE; ++e) if (l[e] > l[i0]) i0 = e;
    int i1 = -1;
    for (int e = 0; e < NE; ++e) if (e != i0 && (i1 < 0 || l[e] > l[i1])) i1 = e;
    float p1 = __expf(l[i1] - l[i0]);
    float s = 1.f + p1;
    tokw[t * 2]     = 1.f / s;
    tokw[t * 2 + 1] = p1 / s;
    int q0 = atomicAdd(&cnt[i0], 1);
    lists[i0 * TT + q0] = t * 2;
    int q1 = atomicAdd(&cnt[i1], 1);
    lists[i1 * TT + q1] = t * 2 + 1;
  }
}

// ---- Stage A: act = silu(xh@w1h^T)*(xh@w2h^T). 128x64dual, BK=32, 3-buf counted-vmcnt ----
__global__ __launch_bounds__(256, 3) void k_ffn1(const _Float16* __restrict__ xh,
                                                 const _Float16* __restrict__ w1h,
                                                 const _Float16* __restrict__ w2h,
                                                 const int* __restrict__ lists,
                                                 const int* __restrict__ cnt,
                                                 _Float16* __restrict__ act) {
  const int rt = blockIdx.x, ct = blockIdx.y, e = blockIdx.z;
  const int count = cnt[e];
  if (rt * 128 >= count) return;
  const int tid = threadIdx.x, lane = tid & 63, wv = tid >> 6;

  __shared__ __align__(16) _Float16 As[3][4096];   // 128 rows x 32 (8KB/buf)
  __shared__ __align__(16) _Float16 B1s[3][2048];  // 64 rows x 32 (4KB/buf)
  __shared__ __align__(16) _Float16 B2s[3][2048];
  __shared__ int row_pair[128];

  if (tid < 128) {
    int rg = rt * 128 + tid;
    row_pair[tid] = (rg < count) ? lists[e * TT + rg] : -1;
  }
  __syncthreads();

  // stage setup: LDS dest linear (base + lane*16B); global src pre-swizzled
  const int pA0 = wv * 2048 + lane * 16, pA1 = pA0 + 1024;
  const int qA0 = swz(pA0), qA1 = swz(pA1);
  const int aR0 = qA0 >> 6, aR1 = qA1 >> 6;          // 0..127
  const int p0 = row_pair[aR0], p1 = row_pair[aR1];
  const _Float16* pa0 = xh + (size_t)(p0 >= 0 ? (p0 >> 1) : 0) * HD + ((qA0 >> 4) & 3) * 8;
  const _Float16* pa1 = xh + (size_t)(p1 >= 0 ? (p1 >> 1) : 0) * HD + ((qA1 >> 4) & 3) * 8;
  const int pB = wv * 1024 + lane * 16;
  const int qB = swz(pB);
  const int bR = qB >> 6;                             // 0..63
  const size_t brow = (size_t)e * FFN + (size_t)ct * 64 + bR;
  const _Float16* pb1 = w1h + brow * HD + ((qB >> 4) & 3) * 8;
  const _Float16* pb2 = w2h + brow * HD + ((qB >> 4) & 3) * 8;

  auto stage = [&](int b, int koff) {
    gl_lds16(pa0 + koff, &As[b][wv * 1024]);
    gl_lds16(pa1 + koff, &As[b][wv * 1024 + 512]);
    gl_lds16(pb1 + koff, &B1s[b][wv * 512]);
    gl_lds16(pb2 + koff, &B2s[b][wv * 512]);
  };

  const f32x4 z4 = {0.f, 0.f, 0.f, 0.f};
  f32x4 acc1[4][2], acc2[4][2];
#pragma unroll
  for (int m = 0; m < 4; ++m)
#pragma unroll
    for (int n = 0; n < 2; ++n) { acc1[m][n] = z4; acc2[m][n] = z4; }

  const int fr = lane & 15, kq = lane >> 4;
  const int wrow = (wv >> 1) * 64, wcol = (wv & 1) * 32;
  int aoff[4], boff[2];
#pragma unroll
  for (int m = 0; m < 4; ++m) aoff[m] = swz((wrow + m * 16 + fr) * 64 + kq * 16) >> 1;
#pragma unroll
  for (int n = 0; n < 2; ++n) boff[n] = swz((wcol + n * 16 + fr) * 64 + kq * 16) >> 1;

  stage(0, 0);
  stage(1, BK);
  WAIT_VM4();
  __builtin_amdgcn_s_barrier();

  const int NS = HD / BK;  // 64
  int buf = 0, sb = 2;
  for (int ks = 0; ks < NS; ++ks) {
    const bool pre = (ks + 2 < NS);
    if (pre) stage(sb, (ks + 2) * BK);
    f16x8 fa[4], fb1[2], fb2[2];
#pragma unroll
    for (int m = 0; m < 4; ++m) fa[m] = *(const f16x8*)&As[buf][aoff[m]];
#pragma unroll
    for (int n = 0; n < 2; ++n) {
      fb1[n] = *(const f16x8*)&B1s[buf][boff[n]];
      fb2[n] = *(const f16x8*)&B2s[buf][boff[n]];
    }
    __builtin_amdgcn_s_setprio(1);
#pragma unroll
    for (int m = 0; m < 4; ++m)
#pragma unroll
      for (int n = 0; n < 2; ++n) {
        acc1[m][n] = __builtin_amdgcn_mfma_f32_16x16x32_f16(fa[m], fb1[n], acc1[m][n], 0, 0, 0);
        acc2[m][n] = __builtin_amdgcn_mfma_f32_16x16x32_f16(fa[m], fb2[n], acc2[m][n], 0, 0, 0);
      }
    __builtin_amdgcn_s_setprio(0);
    if (ks + 1 < NS) {
      if (pre) { WAIT_VM4(); } else { WAIT_VM0(); }
      __builtin_amdgcn_s_barrier();
    }
    buf = (buf == 2) ? 0 : buf + 1;
    sb  = (sb  == 2) ? 0 : sb + 1;
  }

  const int rbase = wrow + kq * 4;
#pragma unroll
  for (int m = 0; m < 4; ++m) {
#pragma unroll
    for (int n = 0; n < 2; ++n) {
      const int col = ct * 64 + wcol + n * 16 + fr;
#pragma unroll
      for (int j = 0; j < 4; ++j) {
        int rl = rbase + m * 16 + j;
        int pr = row_pair[rl];
        if (pr >= 0) {
          float h1 = acc1[m][n][j], h2 = acc2[m][n][j];
          float sv = h1 / (1.f + __expf(-h1));
          act[(size_t)pr * FFN + col] = (_Float16)(sv * h2);
        }
      }
    }
  }
}

// ---- Stage B: out += w * (act @ fc2h^T). 128x128, BK=32, 3-buf counted-vmcnt ----
__global__ __launch_bounds__(256, 3) void k_ffn2(const _Float16* __restrict__ act,
                                                 const _Float16* __restrict__ w3h,
                                                 const int* __restrict__ lists,
                                                 const int* __restrict__ cnt,
                                                 const float* __restrict__ tokw,
                                                 float* __restrict__ out) {
  const int rt = blockIdx.x, ct = blockIdx.y, e = blockIdx.z;
  const int count = cnt[e];
  if (rt * 128 >= count) return;
  const int tid = threadIdx.x, lane = tid & 63, wv = tid >> 6;

  __shared__ __align__(16) _Float16 As[3][4096];
  __shared__ __align__(16) _Float16 Bs[3][4096];
  __shared__ int row_pair[128];
  __shared__ float row_w[128];

  if (tid < 128) {
    int rg = rt * 128 + tid;
    int pr = (rg < count) ? lists[e * TT + rg] : -1;
    row_pair[tid] = pr;
    row_w[tid] = (pr >= 0) ? tokw[pr] : 0.f;
  }
  __syncthreads();

  const int pA0 = wv * 2048 + lane * 16, pA1 = pA0 + 1024;
  const int qA0 = swz(pA0), qA1 = swz(pA1);
  const int aR0 = qA0 >> 6, aR1 = qA1 >> 6;
  const int p0 = row_pair[aR0], p1 = row_pair[aR1];
  const _Float16* pa0 = act + (size_t)(p0 >= 0 ? p0 : 0) * FFN + ((qA0 >> 4) & 3) * 8;
  const _Float16* pa1 = act + (size_t)(p1 >= 0 ? p1 : 0) * FFN + ((qA1 >> 4) & 3) * 8;
  const int bR0 = qA0 >> 6, bR1 = qA1 >> 6;
  const _Float16* pb0 = w3h + ((size_t)e * HD + (size_t)ct * 128 + bR0) * FFN + ((qA0 >> 4) & 3) * 8;
  const _Float16* pb1 = w3h + ((size_t)e * HD + (size_t)ct * 128 + bR1) * FFN + ((qA1 >> 4) & 3) * 8;

  auto stage = [&](int b, int koff) {
    gl_lds16(pa0 + koff, &As[b][wv * 1024]);
    gl_lds16(pa1 + koff, &As[b][wv * 1024 + 512]);
    gl_lds16(pb0 + koff, &Bs[b][wv * 1024]);
    gl_lds16(pb1 + koff, &Bs[b][wv * 1024 + 512]);
  };

  const f32x4 z4 = {0.f, 0.f, 0.f, 0.f};
  f32x4 acc[4][4];
#pragma unroll
  for (int m = 0; m < 4; ++m)
#pragma unroll
    for (int n = 0; n < 4; ++n) acc[m][n] = z4;

  const int fr = lane & 15, kq = lane >> 4;
  const int wrow = (wv >> 1) * 64, wcol = (wv & 1) * 64;
  int aoff[4], boff[4];
#pragma unroll
  for (int m = 0; m < 4; ++m) aoff[m] = swz((wrow + m * 16 + fr) * 64 + kq * 16) >> 1;
#pragma unroll
  for (int n = 0; n < 4; ++n) boff[n] = swz((wcol + n * 16 + fr) * 64 + kq * 16) >> 1;

  stage(0, 0);
  stage(1, BK);
  WAIT_VM4();
  __builtin_amdgcn_s_barrier();

  const int NS = FFN / BK;  // 176
  int buf = 0, sb = 2;
  for (int ks = 0; ks < NS; ++ks) {
    const bool pre = (ks + 2 < NS);
    if (pre) stage(sb, (ks + 2) * BK);
    f16x8 fa[4], fb[4];
#pragma unroll
    for (int m = 0; m < 4; ++m) fa[m] = *(const f16x8*)&As[buf][aoff[m]];
#pragma unroll
    for (int n = 0; n < 4; ++n) fb[n] = *(const f16x8*)&Bs[buf][boff[n]];
    __builtin_amdgcn_s_setprio(1);
#pragma unroll
    for (int m = 0; m < 4; ++m)
#pragma unroll
      for (int n = 0; n < 4; ++n)
        acc[m][n] = __builtin_amdgcn_mfma_f32_16x16x32_f16(fa[m], fb[n], acc[m][n], 0, 0, 0);
    __builtin_amdgcn_s_setprio(0);
    if (ks + 1 < NS) {
      if (pre) { WAIT_VM4(); } else { WAIT_VM0(); }
      __builtin_amdgcn_s_barrier();
    }
    buf = (buf == 2) ? 0 : buf + 1;
    sb  = (sb  == 2) ? 0 : sb + 1;
  }

  const int rbase = wrow + kq * 4;
#pragma unroll
  for (int m = 0; m < 4; ++m) {
#pragma unroll
    for (int n = 0; n < 4; ++n) {
      const int col = ct * 128 + wcol + n * 16 + fr;
#pragma unroll
      for (int j = 0; j < 4; ++j) {
        int rl = rbase + m * 16 + j;
        int pr = row_pair[rl];
        if (pr >= 0) {
          float v = acc[m][n][j] * row_w[rl];
          unsafeAtomicAdd(out + (size_t)(pr >> 1) * HD + col, v);
        }
      }
    }
  }
}

extern "C" void kernel_launch(void* const* d_in, const int* in_sizes, int n_in,
                              void* d_out, int out_size, void* d_ws, size_t ws_size,
                              hipStream_t stream) {
  (void)in_sizes; (void)n_in; (void)out_size; (void)ws_size;
  const float* x    = (const float*)d_in[0];
  const float* wg   = (const float*)d_in[1];
  const float* wge  = (const float*)d_in[2];
  const float* fc11 = (const float*)d_in[3];
  const float* fc12 = (const float*)d_in[4];
  const float* fc2  = (const float*)d_in[5];
  float* out    = (float*)d_out;
  float* logits = out + (size_t)TT * HD;

  char* ws = (char*)d_ws;
  float* wr      = (float*)(ws + OFF_WR);
  int*   cnt     = (int*)(ws + OFF_CNT);
  int*   lists   = (int*)(ws + OFF_LISTS);
  float* tokw    = (float*)(ws + OFF_TOKW);
  _Float16* act  = (_Float16*)(ws + OFF_ACT);
  _Float16* xh   = (_Float16*)(ws + OFF_XH);
  _Float16* w1h  = (_Float16*)(ws + OFF_W1H);
  _Float16* w2h  = (_Float16*)(ws + OFF_W2H);
  _Float16* w3h  = (_Float16*)(ws + OFF_W3H);

  hipMemsetAsync(out, 0, (size_t)TT * HD * sizeof(float), stream);
  hipMemsetAsync(cnt, 0, NE * sizeof(int), stream);

  k_prep<<<dim3((HD * NE + 255) / 256), 256, 0, stream>>>(wg, wge, wr);
  k_router<<<dim3(TT), 256, 0, stream>>>(x, wr, logits, tokw, lists, cnt);

  const long nX  = (long)TT * HD / 8;
  const long nW1 = (long)NE * FFN * HD / 8;
  k_cvt<<<dim3(2048), 256, 0, stream>>>(x, xh, nX);
  k_cvt<<<dim3(2048), 256, 0, stream>>>(fc11, w1h, nW1);
  k_cvt<<<dim3(2048), 256, 0, stream>>>(fc12, w2h, nW1);

  k_ffn1<<<dim3(TT / 128, FFN / 64, NE), 256, 0, stream>>>(xh, w1h, w2h, lists, cnt, act);

  k_cvt<<<dim3(2048), 256, 0, stream>>>(fc2, w3h, nW1);

  k_ffn2<<<dim3(TT / 128, HD / 128, NE), 256, 0, stream>>>(act, w3h, lists, cnt, tokw, out);
}